// Round 6
// baseline (63.974 us; speedup 1.0000x reference)
//
#include <hip/hip_runtime.h>

#define NN 16
#define NO 32
#define XCOLS 133

typedef _Float16 h2 __attribute__((ext_vector_type(2)));

static __device__ __forceinline__ h2 pk(float a, float b) {
    return __builtin_bit_cast(h2, __builtin_amdgcn_cvt_pkrtz(a, b));
}
static __device__ __forceinline__ float dot2(h2 a, h2 b, float c) {
    return __builtin_amdgcn_fdot2(a, b, c, false);
}
static __device__ __forceinline__ unsigned h2u(h2 v) { return __builtin_bit_cast(unsigned, v); }
static __device__ __forceinline__ h2 u2h(unsigned v) { return __builtin_bit_cast(h2, v); }

// packed-weight dword offsets (identical layout in d_ws and in the LDS copy)
#define L_PNW1  0      // [2][64]   f16 pairs along K
#define L_PNW2  128    // [32][16]
#define L_RNW1T 640    // [64][8]   transposed: [fout][K-pair]
#define L_RNW2  1152   // [32][8]
#define L_POW1  1408   // [1][64]
#define L_POW2  1472   // [32][16]
#define L_ROW1T 1984   // [64][8]
#define L_ROW2  2496   // [32][8]
#define L_PSW1T 2752   // [64][12]  (9 used, 3 zero-pad)
#define L_PSW2  3520   // [32][64]
#define L_PSW3  5568   // [32][2]
#define L_BIAS  5632   // f32: pnb1+0 rnb1+64 pob1+128 rob1+192 psb1+256 psb2+320 pnb2+384 rnb2+400 pob2+408 rob2+424 psb3+432
#define W_TOTAL 6080

// LDS regions (dword offsets)
#define LX_XS  6080    // 32*65 = 2080 (pad-65: bank = (cp+e)%32, conflict-free)
#define LX_U   8160    // 8 waves * 8 pair-slots * 64 elems = 4096
#define LX_F   12256   // 2048: rn/ro pair-slots [8][4][64], later float4[8][64]
#define LDS_DW 14304   // 57216 B -> 2 blocks/CU

__global__ void prep_weights(
    const float* __restrict__ pnW1, const float* __restrict__ pnW2,
    const float* __restrict__ rnW1, const float* __restrict__ rnW2,
    const float* __restrict__ poW1, const float* __restrict__ poW2,
    const float* __restrict__ roW1, const float* __restrict__ roW2,
    const float* __restrict__ psW1, const float* __restrict__ psW2,
    const float* __restrict__ psW3,
    const float* __restrict__ pnb1, const float* __restrict__ pnb2,
    const float* __restrict__ rnb1, const float* __restrict__ rnb2,
    const float* __restrict__ pob1, const float* __restrict__ pob2,
    const float* __restrict__ rob1, const float* __restrict__ rob2,
    const float* __restrict__ psb1, const float* __restrict__ psb2,
    const float* __restrict__ psb3, unsigned* __restrict__ ws)
{
    const int t = threadIdx.x;  // 256 threads
    for (int i = t; i < 128; i += 256) {                 // PNW1 [2][64]
        int p = i >> 6, c = i & 63;
        ws[L_PNW1 + i] = h2u(pk(pnW1[(2*p)*64 + c], pnW1[(2*p+1)*64 + c]));
    }
    for (int i = t; i < 512; i += 256) {                 // PNW2 [32][16]
        int p = i >> 4, q = i & 15;
        ws[L_PNW2 + i] = h2u(pk(pnW2[(2*p)*16 + q], pnW2[(2*p+1)*16 + q]));
    }
    for (int i = t; i < 512; i += 256) {                 // RNW1T [64][8]
        int f = i >> 3, p = i & 7;
        ws[L_RNW1T + i] = h2u(pk(rnW1[(2*p)*64 + f], rnW1[(2*p+1)*64 + f]));
    }
    for (int i = t; i < 256; i += 256) {                 // RNW2 [32][8]
        int p = i >> 3, r = i & 7;
        ws[L_RNW2 + i] = h2u(pk(rnW2[(2*p)*8 + r], rnW2[(2*p+1)*8 + r]));
    }
    for (int i = t; i < 64; i += 256)                    // POW1 [1][64]
        ws[L_POW1 + i] = h2u(pk(poW1[i], poW1[64 + i]));
    for (int i = t; i < 512; i += 256) {                 // POW2 [32][16]
        int p = i >> 4, q = i & 15;
        ws[L_POW2 + i] = h2u(pk(poW2[(2*p)*16 + q], poW2[(2*p+1)*16 + q]));
    }
    for (int i = t; i < 512; i += 256) {                 // ROW1T [64][8]
        int f = i >> 3, p = i & 7;
        ws[L_ROW1T + i] = h2u(pk(roW1[(2*p)*64 + f], roW1[(2*p+1)*64 + f]));
    }
    for (int i = t; i < 256; i += 256) {                 // ROW2 [32][8]
        int p = i >> 3, r = i & 7;
        ws[L_ROW2 + i] = h2u(pk(roW2[(2*p)*8 + r], roW2[(2*p+1)*8 + r]));
    }
    for (int i = t; i < 768; i += 256) {                 // PSW1T [64][12]
        int f = i / 12, p = i - 12 * (i / 12);
        ws[L_PSW1T + i] = (p < 9) ? h2u(pk(psW1[(2*p)*64 + f], psW1[(2*p+1)*64 + f])) : 0u;
    }
    for (int i = t; i < 2048; i += 256) {                // PSW2 [32][64]
        int p = i >> 6, c = i & 63;
        ws[L_PSW2 + i] = h2u(pk(psW2[(2*p)*64 + c], psW2[(2*p+1)*64 + c]));
    }
    for (int i = t; i < 64; i += 256) {                  // PSW3 [32][2]
        int p = i >> 1, c = i & 1;
        ws[L_PSW3 + i] = h2u(pk(psW3[(2*p)*2 + c], psW3[(2*p+1)*2 + c]));
    }
    for (int i = t; i < 64; i += 256) {                  // biases (f32 bits)
        ws[L_BIAS +   0 + i] = __float_as_uint(pnb1[i]);
        ws[L_BIAS +  64 + i] = __float_as_uint(rnb1[i]);
        ws[L_BIAS + 128 + i] = __float_as_uint(pob1[i]);
        ws[L_BIAS + 192 + i] = __float_as_uint(rob1[i]);
        ws[L_BIAS + 256 + i] = __float_as_uint(psb1[i]);
        ws[L_BIAS + 320 + i] = __float_as_uint(psb2[i]);
    }
    if (t < 16) ws[L_BIAS + 384 + t] = __float_as_uint(pnb2[t]);
    if (t < 8)  ws[L_BIAS + 400 + t] = __float_as_uint(rnb2[t]);
    if (t < 16) ws[L_BIAS + 408 + t] = __float_as_uint(pob2[t]);
    if (t < 8)  ws[L_BIAS + 424 + t] = __float_as_uint(rob2[t]);
    if (t < 2)  ws[L_BIAS + 432 + t] = __float_as_uint(psb3[t]);
}

// 512 threads = 8 waves; wave w owns fout slice [8w, 8w+8). All weights/biases
// read from an LDS copy via broadcast ds_read_b128 into VGPRs (no SGPR operands
// in dot2, no scalar-stream stalls). xs pad-65 layout: read addr = l*4 + imm.
__global__ __launch_bounds__(512, 4) void barrier_net_kernel(
    const float* __restrict__ x, const float* __restrict__ noise,
    const unsigned* __restrict__ wsu, float* __restrict__ out)
{
    __shared__ unsigned lds[LDS_DW];

    const int tid = threadIdx.x;
    const int l   = tid & 63;
    const int w   = __builtin_amdgcn_readfirstlane(tid >> 6);
    const int fb  = w * 8, fp0 = w * 4;
    const int e0  = blockIdx.x * 64;

    unsigned* wl = lds;
    const float* bl = (const float*)(lds + L_BIAS);
    unsigned* xs = lds + LX_XS;
    unsigned* U  = lds + LX_U;
    unsigned* Fu = lds + LX_F;

    // weights + biases -> LDS
    for (int i = tid; i < W_TOTAL; i += 512) wl[i] = wsu[i];

    // stage neighbor cols [5,69) as f16 pairs
    const float* __restrict__ src = x + (size_t)e0 * XCOLS;
    #pragma unroll
    for (int it = 0; it < 4; ++it) {
        const int idx = it * 512 + tid;
        const int ee = idx >> 5, cp = idx & 31;
        const float* p = src + (size_t)ee * XCOLS + 5 + 2 * cp;
        xs[cp * 65 + ee] = h2u(pk(p[0], p[1]));
    }
    const float g0 = x[(size_t)(e0 + l) * XCOLS + 1];
    const float g1 = x[(size_t)(e0 + l) * XCOLS + 2];
    __syncthreads();  // B1

    float bar0 = 0.f, bar1 = 0.f;

    // ============ P1: neigh L1 -> pn partial -> U[w][0..7]; barrier j=2w,2w+1 ====
    {
        const uint4 wa0 = *(const uint4*)&wl[L_PNW1 + fb];
        const uint4 wa1 = *(const uint4*)&wl[L_PNW1 + fb + 4];
        const uint4 wb0 = *(const uint4*)&wl[L_PNW1 + 64 + fb];
        const uint4 wb1 = *(const uint4*)&wl[L_PNW1 + 64 + fb + 4];
        const h2 w0[8] = {u2h(wa0.x),u2h(wa0.y),u2h(wa0.z),u2h(wa0.w),
                          u2h(wa1.x),u2h(wa1.y),u2h(wa1.z),u2h(wa1.w)};
        const h2 w1[8] = {u2h(wb0.x),u2h(wb0.y),u2h(wb0.z),u2h(wb0.w),
                          u2h(wb1.x),u2h(wb1.y),u2h(wb1.z),u2h(wb1.w)};
        const float4 b0 = *(const float4*)&bl[0 + fb];
        const float4 b1 = *(const float4*)&bl[0 + fb + 4];
        const float bn[8] = {b0.x,b0.y,b0.z,b0.w,b1.x,b1.y,b1.z,b1.w};
        float sn[8] = {0.f,0.f,0.f,0.f,0.f,0.f,0.f,0.f};
        #pragma unroll
        for (int j = 0; j < NN; ++j) {
            const h2 h01 = u2h(xs[(2*j)*65 + l]);
            const h2 h23 = u2h(xs[(2*j+1)*65 + l]);
            #pragma unroll
            for (int f = 0; f < 8; ++f) {
                float t = dot2(h01, w0[f], bn[f]);
                t = dot2(h23, w1[f], t);
                sn[f] += fmaxf(t, 0.f);
            }
        }
        #pragma unroll
        for (int jj = 0; jj < 2; ++jj) {
            const h2 h01 = u2h(xs[(2*(2*w+jj))*65 + l]);
            const float v0 = (float)h01[0], v1 = (float)h01[1];
            const float nrm = sqrtf(v0*v0 + v1*v1);
            const float cc = 0.01f * __builtin_amdgcn_rcpf(nrm * (nrm - 0.3f));
            bar0 -= cc * v0;
            bar1 -= cc * v1;
        }
        h2 snp[4];
        #pragma unroll
        for (int i = 0; i < 4; ++i) snp[i] = pk(sn[2*i], sn[2*i+1]);
        float pn[16];
        #pragma unroll
        for (int q = 0; q < 16; ++q) pn[q] = 0.f;
        #pragma unroll
        for (int i = 0; i < 4; ++i) {
            const int o = L_PNW2 + (fp0 + i) * 16;
            const uint4 q0 = *(const uint4*)&wl[o];
            const uint4 q1 = *(const uint4*)&wl[o + 4];
            const uint4 q2 = *(const uint4*)&wl[o + 8];
            const uint4 q3 = *(const uint4*)&wl[o + 12];
            const h2 wq[16] = {u2h(q0.x),u2h(q0.y),u2h(q0.z),u2h(q0.w),
                               u2h(q1.x),u2h(q1.y),u2h(q1.z),u2h(q1.w),
                               u2h(q2.x),u2h(q2.y),u2h(q2.z),u2h(q2.w),
                               u2h(q3.x),u2h(q3.y),u2h(q3.z),u2h(q3.w)};
            #pragma unroll
            for (int q = 0; q < 16; ++q) pn[q] = dot2(snp[i], wq[q], pn[q]);
        }
        #pragma unroll
        for (int p = 0; p < 8; ++p)
            U[(w*8+p)*64 + l] = h2u(pk(pn[2*p], pn[2*p+1]));
    }
    __syncthreads();  // B2

    // ============ P2: pn full -> rn slice -> Fu[w][0..3]; stage obst ============
    {
        h2 pnp[8];
        #pragma unroll
        for (int p = 0; p < 8; ++p) {
            const float2 b2 = *(const float2*)&bl[384 + 2*p];
            h2 acc = pk(16.f * b2.x, 16.f * b2.y);
            #pragma unroll
            for (int w2 = 0; w2 < 8; ++w2) acc = acc + u2h(U[(w2*8+p)*64 + l]);
            pnp[p] = acc;
        }
        const float4 b0 = *(const float4*)&bl[64 + fb];
        const float4 b1 = *(const float4*)&bl[64 + fb + 4];
        const float bn2[8] = {b0.x,b0.y,b0.z,b0.w,b1.x,b1.y,b1.z,b1.w};
        float tv[8];
        #pragma unroll
        for (int f = 0; f < 8; ++f) {
            const int o = L_RNW1T + (fb + f) * 8;
            const uint4 qa = *(const uint4*)&wl[o];
            const uint4 qb = *(const uint4*)&wl[o + 4];
            const h2 wr[8] = {u2h(qa.x),u2h(qa.y),u2h(qa.z),u2h(qa.w),
                              u2h(qb.x),u2h(qb.y),u2h(qb.z),u2h(qb.w)};
            float t = bn2[f];
            #pragma unroll
            for (int p = 0; p < 8; ++p) t = dot2(pnp[p], wr[p], t);
            tv[f] = fmaxf(t, 0.f);
        }
        h2 tp[4];
        #pragma unroll
        for (int i = 0; i < 4; ++i) tp[i] = pk(tv[2*i], tv[2*i+1]);
        float rp[8];
        #pragma unroll
        for (int r = 0; r < 8; ++r) rp[r] = 0.f;
        #pragma unroll
        for (int i = 0; i < 4; ++i) {
            const int o = L_RNW2 + (fp0 + i) * 8;
            const uint4 qa = *(const uint4*)&wl[o];
            const uint4 qb = *(const uint4*)&wl[o + 4];
            const h2 wv[8] = {u2h(qa.x),u2h(qa.y),u2h(qa.z),u2h(qa.w),
                              u2h(qb.x),u2h(qb.y),u2h(qb.z),u2h(qb.w)};
            #pragma unroll
            for (int r = 0; r < 8; ++r) rp[r] = dot2(tp[i], wv[r], rp[r]);
        }
        #pragma unroll
        for (int p = 0; p < 4; ++p)
            Fu[(w*4+p)*64 + l] = h2u(pk(rp[2*p], rp[2*p+1]));
        // stage obstacle cols [69,133) into xs (neigh data fully consumed in P1)
        #pragma unroll
        for (int it = 0; it < 4; ++it) {
            const int idx = it * 512 + tid;
            const int ee = idx >> 5, cp = idx & 31;
            const float* p = src + (size_t)ee * XCOLS + 69 + 2 * cp;
            xs[cp * 65 + ee] = h2u(pk(p[0], p[1]));
        }
    }
    __syncthreads();  // B3

    // ============ P3: rn full (keep); obst L1 -> po partial -> U; barrier 4j ====
    h2 rnp[4];
    {
        #pragma unroll
        for (int p = 0; p < 4; ++p) {
            const float2 b2 = *(const float2*)&bl[400 + 2*p];
            h2 acc = pk(b2.x, b2.y);
            #pragma unroll
            for (int w2 = 0; w2 < 8; ++w2) acc = acc + u2h(Fu[(w2*4+p)*64 + l]);
            rnp[p] = acc;
        }
        const uint4 qa = *(const uint4*)&wl[L_POW1 + fb];
        const uint4 qb = *(const uint4*)&wl[L_POW1 + fb + 4];
        const h2 wo[8] = {u2h(qa.x),u2h(qa.y),u2h(qa.z),u2h(qa.w),
                          u2h(qb.x),u2h(qb.y),u2h(qb.z),u2h(qb.w)};
        const float4 b0 = *(const float4*)&bl[128 + fb];
        const float4 b1 = *(const float4*)&bl[128 + fb + 4];
        const float bo[8] = {b0.x,b0.y,b0.z,b0.w,b1.x,b1.y,b1.z,b1.w};
        float so[8] = {0.f,0.f,0.f,0.f,0.f,0.f,0.f,0.f};
        #pragma unroll
        for (int j = 0; j < NO; ++j) {
            const h2 hp2 = u2h(xs[j*65 + l]);
            #pragma unroll
            for (int f = 0; f < 8; ++f) {
                const float t = dot2(hp2, wo[f], bo[f]);
                so[f] += fmaxf(t, 0.f);
            }
        }
        #pragma unroll
        for (int jj = 0; jj < 4; ++jj) {
            const h2 hp2 = u2h(xs[(4*w+jj)*65 + l]);
            const float v0 = (float)hp2[0], v1 = (float)hp2[1];
            const float nrm = sqrtf(v0*v0 + v1*v1);
            const float cc = 0.01f * __builtin_amdgcn_rcpf(nrm * (nrm - 0.5f));
            bar0 -= cc * v0;
            bar1 -= cc * v1;
        }
        h2 sop[4];
        #pragma unroll
        for (int i = 0; i < 4; ++i) sop[i] = pk(so[2*i], so[2*i+1]);
        float po[16];
        #pragma unroll
        for (int q = 0; q < 16; ++q) po[q] = 0.f;
        #pragma unroll
        for (int i = 0; i < 4; ++i) {
            const int o = L_POW2 + (fp0 + i) * 16;
            const uint4 q0 = *(const uint4*)&wl[o];
            const uint4 q1 = *(const uint4*)&wl[o + 4];
            const uint4 q2 = *(const uint4*)&wl[o + 8];
            const uint4 q3 = *(const uint4*)&wl[o + 12];
            const h2 wq[16] = {u2h(q0.x),u2h(q0.y),u2h(q0.z),u2h(q0.w),
                               u2h(q1.x),u2h(q1.y),u2h(q1.z),u2h(q1.w),
                               u2h(q2.x),u2h(q2.y),u2h(q2.z),u2h(q2.w),
                               u2h(q3.x),u2h(q3.y),u2h(q3.z),u2h(q3.w)};
            #pragma unroll
            for (int q = 0; q < 16; ++q) po[q] = dot2(sop[i], wq[q], po[q]);
        }
        #pragma unroll
        for (int p = 0; p < 8; ++p)
            U[(w*8+p)*64 + l] = h2u(pk(po[2*p], po[2*p+1]));
    }
    __syncthreads();  // B4

    // ============ P4: po full -> ro slice -> Fu[w][0..3] ============
    {
        h2 pop[8];
        #pragma unroll
        for (int p = 0; p < 8; ++p) {
            const float2 b2 = *(const float2*)&bl[408 + 2*p];
            h2 acc = pk(32.f * b2.x, 32.f * b2.y);
            #pragma unroll
            for (int w2 = 0; w2 < 8; ++w2) acc = acc + u2h(U[(w2*8+p)*64 + l]);
            pop[p] = acc;
        }
        const float4 b0 = *(const float4*)&bl[192 + fb];
        const float4 b1 = *(const float4*)&bl[192 + fb + 4];
        const float bn2[8] = {b0.x,b0.y,b0.z,b0.w,b1.x,b1.y,b1.z,b1.w};
        float tv[8];
        #pragma unroll
        for (int f = 0; f < 8; ++f) {
            const int o = L_ROW1T + (fb + f) * 8;
            const uint4 qa = *(const uint4*)&wl[o];
            const uint4 qb = *(const uint4*)&wl[o + 4];
            const h2 wr[8] = {u2h(qa.x),u2h(qa.y),u2h(qa.z),u2h(qa.w),
                              u2h(qb.x),u2h(qb.y),u2h(qb.z),u2h(qb.w)};
            float t = bn2[f];
            #pragma unroll
            for (int p = 0; p < 8; ++p) t = dot2(pop[p], wr[p], t);
            tv[f] = fmaxf(t, 0.f);
        }
        h2 tp[4];
        #pragma unroll
        for (int i = 0; i < 4; ++i) tp[i] = pk(tv[2*i], tv[2*i+1]);
        float op[8];
        #pragma unroll
        for (int r = 0; r < 8; ++r) op[r] = 0.f;
        #pragma unroll
        for (int i = 0; i < 4; ++i) {
            const int o = L_ROW2 + (fp0 + i) * 8;
            const uint4 qa = *(const uint4*)&wl[o];
            const uint4 qb = *(const uint4*)&wl[o + 4];
            const h2 wv[8] = {u2h(qa.x),u2h(qa.y),u2h(qa.z),u2h(qa.w),
                              u2h(qb.x),u2h(qb.y),u2h(qb.z),u2h(qb.w)};
            #pragma unroll
            for (int r = 0; r < 8; ++r) op[r] = dot2(tp[i], wv[r], op[r]);
        }
        #pragma unroll
        for (int p = 0; p < 4; ++p)
            Fu[(w*4+p)*64 + l] = h2u(pk(op[2*p], op[2*p+1]));
    }
    __syncthreads();  // B5

    // ============ P5: ro full; psi L1 -> ha -> U[w][0..3] ============
    {
        h2 hp[9];
        #pragma unroll
        for (int p = 0; p < 4; ++p) hp[p] = rnp[p];
        #pragma unroll
        for (int p = 0; p < 4; ++p) {
            const float2 b2 = *(const float2*)&bl[424 + 2*p];
            h2 acc = pk(b2.x, b2.y);
            #pragma unroll
            for (int w2 = 0; w2 < 8; ++w2) acc = acc + u2h(Fu[(w2*4+p)*64 + l]);
            hp[4 + p] = acc;
        }
        hp[8] = pk(g0, g1);
        const float4 b0 = *(const float4*)&bl[256 + fb];
        const float4 b1 = *(const float4*)&bl[256 + fb + 4];
        const float bp[8] = {b0.x,b0.y,b0.z,b0.w,b1.x,b1.y,b1.z,b1.w};
        float ha[8];
        #pragma unroll
        for (int f = 0; f < 8; ++f) {
            const int o = L_PSW1T + (fb + f) * 12;
            const uint4 qa = *(const uint4*)&wl[o];
            const uint4 qb = *(const uint4*)&wl[o + 4];
            const uint4 qc = *(const uint4*)&wl[o + 8];
            const h2 wp[9] = {u2h(qa.x),u2h(qa.y),u2h(qa.z),u2h(qa.w),
                              u2h(qb.x),u2h(qb.y),u2h(qb.z),u2h(qb.w),
                              u2h(qc.x)};
            float t = bp[f];
            #pragma unroll
            for (int p = 0; p < 9; ++p) t = dot2(hp[p], wp[p], t);
            ha[f] = fmaxf(t, 0.f);
        }
        #pragma unroll
        for (int p = 0; p < 4; ++p)
            U[(w*8+p)*64 + l] = h2u(pk(ha[2*p], ha[2*p+1]));
    }
    __syncthreads();  // B6

    // ============ P6: psi L2 slice + L3 partials -> F (float4) ============
    {
        const float4 c0 = *(const float4*)&bl[320 + fb];
        const float4 c1 = *(const float4*)&bl[320 + fb + 4];
        float t2[8] = {c0.x,c0.y,c0.z,c0.w,c1.x,c1.y,c1.z,c1.w};
        #pragma unroll
        for (int pg = 0; pg < 32; ++pg) {
            const h2 hap = u2h(U[((pg>>2)*8 + (pg&3))*64 + l]);
            const int o = L_PSW2 + pg * 64 + fb;
            const uint4 qa = *(const uint4*)&wl[o];
            const uint4 qb = *(const uint4*)&wl[o + 4];
            const h2 wv[8] = {u2h(qa.x),u2h(qa.y),u2h(qa.z),u2h(qa.w),
                              u2h(qb.x),u2h(qb.y),u2h(qb.z),u2h(qb.w)};
            #pragma unroll
            for (int f2 = 0; f2 < 8; ++f2) t2[f2] = dot2(hap, wv[f2], t2[f2]);
        }
        h2 tpp[4];
        #pragma unroll
        for (int i = 0; i < 4; ++i)
            tpp[i] = pk(fmaxf(t2[2*i], 0.f), fmaxf(t2[2*i+1], 0.f));
        float o0p = 0.f, o1p = 0.f;
        #pragma unroll
        for (int i = 0; i < 4; ++i) {
            const h2 wA = u2h(wl[L_PSW3 + (fp0 + i) * 2 + 0]);
            const h2 wB = u2h(wl[L_PSW3 + (fp0 + i) * 2 + 1]);
            o0p = dot2(tpp[i], wA, o0p);
            o1p = dot2(tpp[i], wB, o1p);
        }
        float4* Ff = (float4*)(lds + LX_F);
        Ff[w * 64 + l] = make_float4(o0p, o1p, bar0, bar1);
    }
    __syncthreads();  // B7

    // ============ P7: finale ============
    if (tid < 128) {
        const int elem = tid >> 1, oi = tid & 1;
        const float4* Ff = (const float4*)(lds + LX_F);
        float o = bl[432 + oi], bb = 0.f;
        #pragma unroll
        for (int w2 = 0; w2 < 8; ++w2) {
            const float4 v = Ff[w2 * 64 + elem];
            o  += oi ? v.y : v.x;
            bb += oi ? v.w : v.z;
        }
        const float e_ = 2.f * tanhf(o);
        const float av = tanhf(e_ + bb + noise[2 * (size_t)e0 + tid]);
        out[2 * (size_t)e0 + tid] = 2.f * av;
    }
}

extern "C" void kernel_launch(void* const* d_in, const int* in_sizes, int n_in,
                              void* d_out, int out_size, void* d_ws, size_t ws_size,
                              hipStream_t stream) {
    const float* x    = (const float*)d_in[0];
    const float* nz   = (const float*)d_in[1];
    const float* pnW1 = (const float*)d_in[2];
    const float* pnb1 = (const float*)d_in[3];
    const float* pnW2 = (const float*)d_in[4];
    const float* pnb2 = (const float*)d_in[5];
    const float* rnW1 = (const float*)d_in[6];
    const float* rnb1 = (const float*)d_in[7];
    const float* rnW2 = (const float*)d_in[8];
    const float* rnb2 = (const float*)d_in[9];
    const float* poW1 = (const float*)d_in[10];
    const float* pob1 = (const float*)d_in[11];
    const float* poW2 = (const float*)d_in[12];
    const float* pob2 = (const float*)d_in[13];
    const float* roW1 = (const float*)d_in[14];
    const float* rob1 = (const float*)d_in[15];
    const float* roW2 = (const float*)d_in[16];
    const float* rob2 = (const float*)d_in[17];
    const float* psW1 = (const float*)d_in[18];
    const float* psb1 = (const float*)d_in[19];
    const float* psW2 = (const float*)d_in[20];
    const float* psb2 = (const float*)d_in[21];
    const float* psW3 = (const float*)d_in[22];
    const float* psb3 = (const float*)d_in[23];

    unsigned* ws = (unsigned*)d_ws;
    hipLaunchKernelGGL(prep_weights, dim3(1), dim3(256), 0, stream,
        pnW1, pnW2, rnW1, rnW2, poW1, poW2, roW1, roW2, psW1, psW2, psW3,
        pnb1, pnb2, rnb1, rnb2, pob1, pob2, rob1, rob2, psb1, psb2, psb3, ws);

    const int b = in_sizes[0] / XCOLS;
    hipLaunchKernelGGL(barrier_net_kernel, dim3(b / 64), dim3(512), 0, stream,
        x, nz, ws, (float*)d_out);
}

// Round 7
// 61.829 us; speedup vs baseline: 1.0347x; 1.0347x over previous
//
#include <hip/hip_runtime.h>

#define NN 16
#define NO 32
#define XCOLS 133

typedef _Float16 h8v __attribute__((ext_vector_type(8)));
typedef float f4v __attribute__((ext_vector_type(4)));

static __device__ __forceinline__ f4v MFMA(h8v a, h8v b, f4v c) {
    return __builtin_amdgcn_mfma_f32_16x16x32_f16(a, b, c, 0, 0, 0);
}

// ---------------------------------------------------------------------------
// prep: pack every weight matrix into MFMA B-fragment arrays in d_ws.
// Fragment layout (16x16x32_f16): lane provides B[k][col] with
//   col = 16*nt + (lane&15),  k = 32*kc + 8*(lane>>4) + j  (j = f16 idx 0..7)
// Stored as [kc*nnt+nt][lane][4 dwords] (each dword = f16 pair, low = even k).
// ---------------------------------------------------------------------------
__global__ void prep_frags(
    const float* __restrict__ pnW1, const float* __restrict__ pnW2,
    const float* __restrict__ rnW1, const float* __restrict__ rnW2,
    const float* __restrict__ poW1, const float* __restrict__ poW2,
    const float* __restrict__ roW1, const float* __restrict__ roW2,
    const float* __restrict__ psW1, const float* __restrict__ psW2,
    const float* __restrict__ psW3, unsigned* __restrict__ ws)
{
    const float* Ws[11] = {pnW1,pnW2,rnW1,rnW2,poW1,poW2,roW1,roW2,psW1,psW2,psW3};
    const int Kr[11]   = {4,64,16,64,2,64,16,64,18,64,64};
    const int Nr[11]   = {64,16,64,8,64,16,64,8,64,64,2};
    const int nkc[11]  = {1,2,1,2,1,2,1,2,1,2,2};
    const int nnt[11]  = {4,1,4,1,4,1,4,1,4,4,1};
    const int base[11] = {0,1024,1536,2560,3072,4096,4608,5632,6144,7168,9216};
    for (int a2 = 0; a2 < 11; ++a2) {
        const float* Wm = Ws[a2];
        const int K = Kr[a2], N = Nr[a2], nt_n = nnt[a2];
        const int n = nkc[a2] * nt_n * 256;
        for (int i = threadIdx.x; i < n; i += blockDim.x) {
            const int d = i & 3, lane = (i >> 2) & 63, t = i >> 8;
            const int nt = t % nt_n, kc = t / nt_n;
            const int k = kc * 32 + 8 * (lane >> 4) + 2 * d;
            const int col = nt * 16 + (lane & 15);
            const float v0 = (k     < K && col < N) ? Wm[(k    ) * N + col] : 0.f;
            const float v1 = (k + 1 < K && col < N) ? Wm[(k + 1) * N + col] : 0.f;
            ws[base[a2] + i] = __builtin_bit_cast(unsigned, __builtin_amdgcn_cvt_pkrtz(v0, v1));
        }
    }
}

// ---------------------------------------------------------------------------
// main kernel: 256 threads = 4 waves; each wave independently processes 16
// elements end-to-end with MFMA. No __syncthreads (all LDS wave-private).
// Per-wave LDS (f16 units): POOL[16][64]@0, TBUF[16][64]@1024,
// PNBUF[16][32]@2048, HBUF[16][32]@2560, BAR(16x2 f32)@3072. Total 3136 f16.
// XOR swizzle: element k of row stored at f16-idx (k ^ ((row&7)<<3)).
// ---------------------------------------------------------------------------
__global__ __launch_bounds__(256, 4) void barrier_net_kernel(
    const float* __restrict__ x, const float* __restrict__ noise,
    const float* __restrict__ pnb1, const float* __restrict__ pnb2,
    const float* __restrict__ rnb1, const float* __restrict__ rnb2,
    const float* __restrict__ pob1, const float* __restrict__ pob2,
    const float* __restrict__ rob1, const float* __restrict__ rob2,
    const float* __restrict__ psb1, const float* __restrict__ psb2,
    const float* __restrict__ psb3,
    const unsigned* __restrict__ wsu, float* __restrict__ out)
{
    __shared__ _Float16 smem[4][3136];

    const int tid = threadIdx.x;
    const int l = tid & 63;
    const int w = tid >> 6;
    const int r = l & 15;   // in-tile row/col lane index
    const int g = l >> 4;   // lane group (k-chunk / row-group)
    const int eb = blockIdx.x * 64 + w * 16;

    _Float16* W = &smem[w][0];
    float* barf = (float*)(W + 3072);
    const h8v* FB = (const h8v*)wsu;   // 16B-granular fragment table

    // zero PNBUF+HBUF (contiguous 1024 f16 = 512 dwords)
    {
        unsigned* z = (unsigned*)(W + 2048);
        #pragma unroll
        for (int i = 0; i < 8; ++i) z[l + 64 * i] = 0u;
    }

    // ================= L1 neighbor: per element e, tile [16pts x K4] ==========
    {
        const h8v Bn0 = FB[0 * 64 + l], Bn1 = FB[1 * 64 + l];
        const h8v Bn2 = FB[2 * 64 + l], Bn3 = FB[3 * 64 + l];
        const float cb0 = pnb1[r], cb1 = pnb1[16 + r], cb2 = pnb1[32 + r], cb3 = pnb1[48 + r];
        for (int e = 0; e < 16; ++e) {
            h8v a = {0,0,0,0,0,0,0,0};
            if (g == 0) {
                const float* px = x + (size_t)(eb + e) * XCOLS + 5 + 4 * r;
                a[0] = (_Float16)px[0]; a[1] = (_Float16)px[1];
                a[2] = (_Float16)px[2]; a[3] = (_Float16)px[3];
            }
            #define L1N_NT(nt, B, cbs) { \
                f4v c = {cbs, cbs, cbs, cbs}; \
                f4v d = MFMA(a, B, c); \
                float s = fmaxf(d[0],0.f)+fmaxf(d[1],0.f)+fmaxf(d[2],0.f)+fmaxf(d[3],0.f); \
                s += __shfl_xor(s, 16); s += __shfl_xor(s, 32); \
                if (g == 0) W[e*64 + ((16*(nt)+r) ^ ((e&7)<<3))] = (_Float16)s; \
            }
            L1N_NT(0, Bn0, cb0) L1N_NT(1, Bn1, cb1) L1N_NT(2, Bn2, cb2) L1N_NT(3, Bn3, cb3)
            #undef L1N_NT
        }
    }

    // ================= stage C: pn = sn @ pnW2 + 16*pnb2  -> PNBUF ============
    {
        h8v a0 = *(const h8v*)&W[r*64 + (( 0 + 8*g) ^ ((r&7)<<3))];
        h8v a1 = *(const h8v*)&W[r*64 + ((32 + 8*g) ^ ((r&7)<<3))];
        h8v b0 = FB[256 + 0 * 64 + l];
        h8v b1 = FB[256 + 1 * 64 + l];
        const float bb = 16.f * pnb2[r];
        f4v c = {bb, bb, bb, bb};
        f4v d = MFMA(a1, b1, MFMA(a0, b0, c));
        #pragma unroll
        for (int q = 0; q < 4; ++q) {
            const int row = 4 * g + q;
            W[2048 + row*32 + (r ^ ((row&3)<<3))] = (_Float16)d[q];
        }
    }

    // ================= D1: t = relu(pn @ rnW1 + rnb1) -> TBUF =================
    {
        h8v a = *(const h8v*)&W[2048 + r*32 + ((8*g) ^ ((r&3)<<3))];
        #pragma unroll
        for (int nt = 0; nt < 4; ++nt) {
            h8v b = FB[384 + nt * 64 + l];
            const float bb = rnb1[16 * nt + r];
            f4v c = {bb, bb, bb, bb};
            f4v d = MFMA(a, b, c);
            #pragma unroll
            for (int q = 0; q < 4; ++q) {
                const int row = 4 * g + q;
                W[1024 + row*64 + ((16*nt + r) ^ ((row&7)<<3))] = (_Float16)fmaxf(d[q], 0.f);
            }
        }
    }
    // ================= D2: rn = t @ rnW2 + rnb2 -> HBUF cols 0..7 =============
    {
        h8v a0 = *(const h8v*)&W[1024 + r*64 + (( 0 + 8*g) ^ ((r&7)<<3))];
        h8v a1 = *(const h8v*)&W[1024 + r*64 + ((32 + 8*g) ^ ((r&7)<<3))];
        h8v b0 = FB[640 + 0 * 64 + l];
        h8v b1 = FB[640 + 1 * 64 + l];
        const float bb = (r < 8) ? rnb2[r & 7] : 0.f;
        f4v c = {bb, bb, bb, bb};
        f4v d = MFMA(a1, b1, MFMA(a0, b0, c));
        if (r < 8) {
            #pragma unroll
            for (int q = 0; q < 4; ++q) {
                const int row = 4 * g + q;
                W[2560 + row*32 + (r ^ ((row&3)<<3))] = (_Float16)d[q];
            }
        }
    }

    // ================= L1 obstacle: 2 tiles [16pts x K2] per element ==========
    {
        const h8v Bo0 = FB[768 + 0*64 + l], Bo1 = FB[768 + 1*64 + l];
        const h8v Bo2 = FB[768 + 2*64 + l], Bo3 = FB[768 + 3*64 + l];
        const float co0 = pob1[r], co1 = pob1[16 + r], co2 = pob1[32 + r], co3 = pob1[48 + r];
        for (int e = 0; e < 16; ++e) {
            h8v a0 = {0,0,0,0,0,0,0,0};
            h8v a1 = {0,0,0,0,0,0,0,0};
            if (g == 0) {
                const float* px = x + (size_t)(eb + e) * XCOLS + 69 + 2 * r;
                a0[0] = (_Float16)px[0];  a0[1] = (_Float16)px[1];
                a1[0] = (_Float16)px[32]; a1[1] = (_Float16)px[33];
            }
            #define L1O_NT(nt, B, cbs) { \
                f4v c = {cbs, cbs, cbs, cbs}; \
                f4v d0 = MFMA(a0, B, c); \
                f4v d1 = MFMA(a1, B, c); \
                float s = fmaxf(d0[0],0.f)+fmaxf(d0[1],0.f)+fmaxf(d0[2],0.f)+fmaxf(d0[3],0.f) \
                        + fmaxf(d1[0],0.f)+fmaxf(d1[1],0.f)+fmaxf(d1[2],0.f)+fmaxf(d1[3],0.f); \
                s += __shfl_xor(s, 16); s += __shfl_xor(s, 32); \
                if (g == 0) W[e*64 + ((16*(nt)+r) ^ ((e&7)<<3))] = (_Float16)s; \
            }
            L1O_NT(0, Bo0, co0) L1O_NT(1, Bo1, co1) L1O_NT(2, Bo2, co2) L1O_NT(3, Bo3, co3)
            #undef L1O_NT
        }
    }

    // ================= C': po = so @ poW2 + 32*pob2 -> PNBUF ==================
    {
        h8v a0 = *(const h8v*)&W[r*64 + (( 0 + 8*g) ^ ((r&7)<<3))];
        h8v a1 = *(const h8v*)&W[r*64 + ((32 + 8*g) ^ ((r&7)<<3))];
        h8v b0 = FB[1024 + 0 * 64 + l];
        h8v b1 = FB[1024 + 1 * 64 + l];
        const float bb = 32.f * pob2[r];
        f4v c = {bb, bb, bb, bb};
        f4v d = MFMA(a1, b1, MFMA(a0, b0, c));
        #pragma unroll
        for (int q = 0; q < 4; ++q) {
            const int row = 4 * g + q;
            W[2048 + row*32 + (r ^ ((row&3)<<3))] = (_Float16)d[q];
        }
    }
    // ================= D1': t = relu(po @ roW1 + rob1) -> TBUF ================
    {
        h8v a = *(const h8v*)&W[2048 + r*32 + ((8*g) ^ ((r&3)<<3))];
        #pragma unroll
        for (int nt = 0; nt < 4; ++nt) {
            h8v b = FB[1152 + nt * 64 + l];
            const float bb = rob1[16 * nt + r];
            f4v c = {bb, bb, bb, bb};
            f4v d = MFMA(a, b, c);
            #pragma unroll
            for (int q = 0; q < 4; ++q) {
                const int row = 4 * g + q;
                W[1024 + row*64 + ((16*nt + r) ^ ((row&7)<<3))] = (_Float16)fmaxf(d[q], 0.f);
            }
        }
    }
    // ================= D2': ro = t @ roW2 + rob2 -> HBUF cols 8..15 ===========
    {
        h8v a0 = *(const h8v*)&W[1024 + r*64 + (( 0 + 8*g) ^ ((r&7)<<3))];
        h8v a1 = *(const h8v*)&W[1024 + r*64 + ((32 + 8*g) ^ ((r&7)<<3))];
        h8v b0 = FB[1408 + 0 * 64 + l];
        h8v b1 = FB[1408 + 1 * 64 + l];
        const float bb = (r < 8) ? rob2[r & 7] : 0.f;
        f4v c = {bb, bb, bb, bb};
        f4v d = MFMA(a1, b1, MFMA(a0, b0, c));
        if (r < 8) {
            #pragma unroll
            for (int q = 0; q < 4; ++q) {
                const int row = 4 * g + q;
                W[2560 + row*32 + ((8 + r) ^ ((row&3)<<3))] = (_Float16)d[q];
            }
        }
    }

    // ================= goal cols 16,17 into HBUF ==============================
    if (g == 0) {
        const float gx = x[(size_t)(eb + r) * XCOLS + 1];
        const float gy = x[(size_t)(eb + r) * XCOLS + 2];
        W[2560 + r*32 + (16 ^ ((r&3)<<3))] = (_Float16)gx;
        W[2560 + r*32 + (17 ^ ((r&3)<<3))] = (_Float16)gy;
    }

    // ================= F: ha = relu(h @ psW1 + psb1) -> TBUF ==================
    {
        h8v a = *(const h8v*)&W[2560 + r*32 + ((8*g) ^ ((r&3)<<3))];
        #pragma unroll
        for (int nt = 0; nt < 4; ++nt) {
            h8v b = FB[1536 + nt * 64 + l];
            const float bb = psb1[16 * nt + r];
            f4v c = {bb, bb, bb, bb};
            f4v d = MFMA(a, b, c);
            #pragma unroll
            for (int q = 0; q < 4; ++q) {
                const int row = 4 * g + q;
                W[1024 + row*64 + ((16*nt + r) ^ ((row&7)<<3))] = (_Float16)fmaxf(d[q], 0.f);
            }
        }
    }
    // ================= G1: t2 = relu(ha @ psW2 + psb2) -> POOL ================
    {
        h8v a0 = *(const h8v*)&W[1024 + r*64 + (( 0 + 8*g) ^ ((r&7)<<3))];
        h8v a1 = *(const h8v*)&W[1024 + r*64 + ((32 + 8*g) ^ ((r&7)<<3))];
        #pragma unroll
        for (int nt = 0; nt < 4; ++nt) {
            h8v b0 = FB[1792 + (0 * 4 + nt) * 64 + l];
            h8v b1 = FB[1792 + (1 * 4 + nt) * 64 + l];
            const float bb = psb2[16 * nt + r];
            f4v c = {bb, bb, bb, bb};
            f4v d = MFMA(a1, b1, MFMA(a0, b0, c));
            #pragma unroll
            for (int q = 0; q < 4; ++q) {
                const int row = 4 * g + q;
                W[row*64 + ((16*nt + r) ^ ((row&7)<<3))] = (_Float16)fmaxf(d[q], 0.f);
            }
        }
    }
    // ================= G2: o = t2 @ psW3 + psb3 (cols 0,1) ====================
    f4v dOut;
    {
        h8v a0 = *(const h8v*)&W[r*64 + (( 0 + 8*g) ^ ((r&7)<<3))];
        h8v a1 = *(const h8v*)&W[r*64 + ((32 + 8*g) ^ ((r&7)<<3))];
        h8v b0 = FB[2304 + 0 * 64 + l];
        h8v b1 = FB[2304 + 1 * 64 + l];
        const float bb = (r < 2) ? psb3[r & 1] : 0.f;
        f4v c = {bb, bb, bb, bb};
        dOut = MFMA(a1, b1, MFMA(a0, b0, c));
    }

    // ================= barrier pass (f32 exact): lane = (elem r, chunk g) =====
    {
        float b0 = 0.f, b1 = 0.f;
        const float* xr = x + (size_t)(eb + r) * XCOLS;
        #pragma unroll
        for (int p = 0; p < 4; ++p) {
            const float v0 = xr[5 + 4 * (4 * g + p)], v1 = xr[5 + 4 * (4 * g + p) + 1];
            const float nrm = sqrtf(v0 * v0 + v1 * v1);
            const float cc = 0.01f * __builtin_amdgcn_rcpf(nrm * (nrm - 0.3f));
            b0 -= cc * v0; b1 -= cc * v1;
        }
        #pragma unroll
        for (int p = 0; p < 8; ++p) {
            const float v0 = xr[69 + 2 * (8 * g + p)], v1 = xr[69 + 2 * (8 * g + p) + 1];
            const float nrm = sqrtf(v0 * v0 + v1 * v1);
            const float cc = 0.01f * __builtin_amdgcn_rcpf(nrm * (nrm - 0.5f));
            b0 -= cc * v0; b1 -= cc * v1;
        }
        b0 += __shfl_xor(b0, 16); b0 += __shfl_xor(b0, 32);
        b1 += __shfl_xor(b1, 16); b1 += __shfl_xor(b1, 32);
        if (g == 0) { barf[r * 2 + 0] = b0; barf[r * 2 + 1] = b1; }
    }

    // ================= finale: lanes with r<2 hold col r for rows 4g+q ========
    if (r < 2) {
        #pragma unroll
        for (int q = 0; q < 4; ++q) {
            const int e = 4 * g + q;
            const float o = dOut[q];
            const float bar = barf[e * 2 + r];
            const float nz = noise[2 * (size_t)(eb + e) + r];
            const float av = tanhf(2.f * tanhf(o) + bar + nz);
            out[2 * (size_t)(eb + e) + r] = 2.f * av;
        }
    }
}

extern "C" void kernel_launch(void* const* d_in, const int* in_sizes, int n_in,
                              void* d_out, int out_size, void* d_ws, size_t ws_size,
                              hipStream_t stream) {
    const float* x    = (const float*)d_in[0];
    const float* nz   = (const float*)d_in[1];
    const float* pnW1 = (const float*)d_in[2];
    const float* pnb1 = (const float*)d_in[3];
    const float* pnW2 = (const float*)d_in[4];
    const float* pnb2 = (const float*)d_in[5];
    const float* rnW1 = (const float*)d_in[6];
    const float* rnb1 = (const float*)d_in[7];
    const float* rnW2 = (const float*)d_in[8];
    const float* rnb2 = (const float*)d_in[9];
    const float* poW1 = (const float*)d_in[10];
    const float* pob1 = (const float*)d_in[11];
    const float* poW2 = (const float*)d_in[12];
    const float* pob2 = (const float*)d_in[13];
    const float* roW1 = (const float*)d_in[14];
    const float* rob1 = (const float*)d_in[15];
    const float* roW2 = (const float*)d_in[16];
    const float* rob2 = (const float*)d_in[17];
    const float* psW1 = (const float*)d_in[18];
    const float* psb1 = (const float*)d_in[19];
    const float* psW2 = (const float*)d_in[20];
    const float* psb2 = (const float*)d_in[21];
    const float* psW3 = (const float*)d_in[22];
    const float* psb3 = (const float*)d_in[23];

    unsigned* ws = (unsigned*)d_ws;
    hipLaunchKernelGGL(prep_frags, dim3(1), dim3(256), 0, stream,
        pnW1, pnW2, rnW1, rnW2, poW1, poW2, roW1, roW2, psW1, psW2, psW3, ws);

    const int b = in_sizes[0] / XCOLS;
    hipLaunchKernelGGL(barrier_net_kernel, dim3(b / 64), dim3(256), 0, stream,
        x, nz, pnb1, pnb2, rnb1, rnb2, pob1, pob2, rob1, rob2,
        psb1, psb2, psb3, ws, (float*)d_out);
}

// Round 8
// 60.557 us; speedup vs baseline: 1.0564x; 1.0210x over previous
//
#include <hip/hip_runtime.h>

#define NN 16
#define NO 32
#define XCOLS 133

typedef _Float16 h8v __attribute__((ext_vector_type(8)));
typedef float f4v __attribute__((ext_vector_type(4)));
typedef unsigned ui4 __attribute__((ext_vector_type(4)));

static __device__ __forceinline__ f4v MFMA(h8v a, h8v b, f4v c) {
    return __builtin_amdgcn_mfma_f32_16x16x32_f16(a, b, c, 0, 0, 0);
}
static __device__ __forceinline__ unsigned pkbits(float a, float b) {
    return __builtin_bit_cast(unsigned, __builtin_amdgcn_cvt_pkrtz(a, b));
}

// ---------------------------------------------------------------------------
// prep: pack weight matrices into MFMA B-fragment arrays in d_ws.
// B[k][col]: col = 16*nt + (lane&15), k = 32*kc + 8*(lane>>4) + j. Zero-padded
// beyond K,N — A-operand garbage at k>=K contributes nothing.
// ---------------------------------------------------------------------------
__global__ void prep_frags(
    const float* __restrict__ pnW1, const float* __restrict__ pnW2,
    const float* __restrict__ rnW1, const float* __restrict__ rnW2,
    const float* __restrict__ poW1, const float* __restrict__ poW2,
    const float* __restrict__ roW1, const float* __restrict__ roW2,
    const float* __restrict__ psW1, const float* __restrict__ psW2,
    const float* __restrict__ psW3, unsigned* __restrict__ ws)
{
    const float* Ws[11] = {pnW1,pnW2,rnW1,rnW2,poW1,poW2,roW1,roW2,psW1,psW2,psW3};
    const int Kr[11]   = {4,64,16,64,2,64,16,64,18,64,64};
    const int Nr[11]   = {64,16,64,8,64,16,64,8,64,64,2};
    const int nkc[11]  = {1,2,1,2,1,2,1,2,1,2,2};
    const int nnt[11]  = {4,1,4,1,4,1,4,1,4,4,1};
    const int base[11] = {0,1024,1536,2560,3072,4096,4608,5632,6144,7168,9216};
    for (int a2 = 0; a2 < 11; ++a2) {
        const float* Wm = Ws[a2];
        const int K = Kr[a2], N = Nr[a2], nt_n = nnt[a2];
        const int n = nkc[a2] * nt_n * 256;
        for (int i = threadIdx.x; i < n; i += blockDim.x) {
            const int d = i & 3, lane = (i >> 2) & 63, t = i >> 8;
            const int nt = t % nt_n, kc = t / nt_n;
            const int k = kc * 32 + 8 * (lane >> 4) + 2 * d;
            const int col = nt * 16 + (lane & 15);
            const float v0 = (k     < K && col < N) ? Wm[(k    ) * N + col] : 0.f;
            const float v1 = (k + 1 < K && col < N) ? Wm[(k + 1) * N + col] : 0.f;
            ws[base[a2] + i] = pkbits(v0, v1);
        }
    }
}

// ---------------------------------------------------------------------------
// main: 256 threads = 4 waves, each wave independently does 16 elements.
// L1: point-loop, elements-as-rows, relu+pool as in-register f32 acc (no
// shuffles, no divergence). Dense chain identical to verified R7 (bases moved).
// Per-wave LDS (f16): POOL[16][64]@0, TBUF[16][64]@1024, PNBUF[16][32]@2048,
// HBUF[16][32]@2560, barf(32 f32)@3072. Total 3136 f16 (25088 B/block).
// ---------------------------------------------------------------------------
__global__ __launch_bounds__(256, 4) void barrier_net_kernel(
    const float* __restrict__ x, const float* __restrict__ noise,
    const float* __restrict__ pnb1, const float* __restrict__ pnb2,
    const float* __restrict__ rnb1, const float* __restrict__ rnb2,
    const float* __restrict__ pob1, const float* __restrict__ pob2,
    const float* __restrict__ rob1, const float* __restrict__ rob2,
    const float* __restrict__ psb1, const float* __restrict__ psb2,
    const float* __restrict__ psb3,
    const unsigned* __restrict__ wsu, float* __restrict__ out)
{
    __shared__ _Float16 smem[4][3136];

    const int tid = threadIdx.x;
    const int l = tid & 63;
    const int w = tid >> 6;
    const int r = l & 15;
    const int g = l >> 4;
    const int eb = blockIdx.x * 64 + w * 16;

    _Float16* W = &smem[w][0];
    float* barf = (float*)(W + 3072);
    const h8v* FB = (const h8v*)wsu;

    {   // zero PNBUF+HBUF
        unsigned* z = (unsigned*)(W + 2048);
        #pragma unroll
        for (int i = 0; i < 8; ++i) z[l + 64 * i] = 0u;
    }

    const size_t xrow = (size_t)(eb + r) * XCOLS;
    float bq0 = 0.f, bq1 = 0.f;

    // ================= L1 neighbor: point-loop ================================
    {
        const h8v B0 = FB[0*64 + l], B1 = FB[1*64 + l];
        const h8v B2 = FB[2*64 + l], B3 = FB[3*64 + l];
        const f4v c0 = {pnb1[r], pnb1[r], pnb1[r], pnb1[r]};
        const f4v c1 = {pnb1[16+r], pnb1[16+r], pnb1[16+r], pnb1[16+r]};
        const f4v c2 = {pnb1[32+r], pnb1[32+r], pnb1[32+r], pnb1[32+r]};
        const f4v c3 = {pnb1[48+r], pnb1[48+r], pnb1[48+r], pnb1[48+r]};
        f4v s0 = {0,0,0,0}, s1 = {0,0,0,0}, s2 = {0,0,0,0}, s3 = {0,0,0,0};
        const float* px = x + xrow + 5;
        #pragma unroll 4
        for (int j = 0; j < NN; ++j) {
            const float v0 = px[4*j], v1 = px[4*j+1], v2 = px[4*j+2], v3 = px[4*j+3];
            ui4 au = {pkbits(v0, v1), pkbits(v2, v3), 0u, 0u};
            const h8v a = __builtin_bit_cast(h8v, au);
            const float nrm = sqrtf(v0*v0 + v1*v1);
            const float cc = 0.01f * __builtin_amdgcn_rcpf(nrm * (nrm - 0.3f));
            bq0 -= cc * v0; bq1 -= cc * v1;
            const f4v d0 = MFMA(a, B0, c0);
            const f4v d1 = MFMA(a, B1, c1);
            const f4v d2 = MFMA(a, B2, c2);
            const f4v d3 = MFMA(a, B3, c3);
            #pragma unroll
            for (int q = 0; q < 4; ++q) {
                s0[q] += fmaxf(d0[q], 0.f); s1[q] += fmaxf(d1[q], 0.f);
                s2[q] += fmaxf(d2[q], 0.f); s3[q] += fmaxf(d3[q], 0.f);
            }
        }
        #pragma unroll
        for (int q = 0; q < 4; ++q) {
            const int e = 4 * g + q;
            const int m = (e & 7) << 3;
            W[e*64 + (( 0 + r) ^ m)] = (_Float16)s0[q];
            W[e*64 + ((16 + r) ^ m)] = (_Float16)s1[q];
            W[e*64 + ((32 + r) ^ m)] = (_Float16)s2[q];
            W[e*64 + ((48 + r) ^ m)] = (_Float16)s3[q];
        }
    }

    // ================= L1 obstacle: point-loop, 2 points/iter =================
    {
        const h8v B0 = FB[768 + 0*64 + l], B1 = FB[768 + 1*64 + l];
        const h8v B2 = FB[768 + 2*64 + l], B3 = FB[768 + 3*64 + l];
        const f4v c0 = {pob1[r], pob1[r], pob1[r], pob1[r]};
        const f4v c1 = {pob1[16+r], pob1[16+r], pob1[16+r], pob1[16+r]};
        const f4v c2 = {pob1[32+r], pob1[32+r], pob1[32+r], pob1[32+r]};
        const f4v c3 = {pob1[48+r], pob1[48+r], pob1[48+r], pob1[48+r]};
        f4v s0 = {0,0,0,0}, s1 = {0,0,0,0}, s2 = {0,0,0,0}, s3 = {0,0,0,0};
        const float* px = x + xrow + 69;
        #pragma unroll 2
        for (int t = 0; t < 16; ++t) {
            const float v0 = px[4*t], v1 = px[4*t+1], v2 = px[4*t+2], v3 = px[4*t+3];
            ui4 au0 = {pkbits(v0, v1), 0u, 0u, 0u};
            ui4 au1 = {pkbits(v2, v3), 0u, 0u, 0u};
            const h8v a0 = __builtin_bit_cast(h8v, au0);
            const h8v a1 = __builtin_bit_cast(h8v, au1);
            const float n0 = sqrtf(v0*v0 + v1*v1);
            const float cc0 = 0.01f * __builtin_amdgcn_rcpf(n0 * (n0 - 0.5f));
            bq0 -= cc0 * v0; bq1 -= cc0 * v1;
            const float n1 = sqrtf(v2*v2 + v3*v3);
            const float cc1 = 0.01f * __builtin_amdgcn_rcpf(n1 * (n1 - 0.5f));
            bq0 -= cc1 * v2; bq1 -= cc1 * v3;
            const f4v d0 = MFMA(a0, B0, c0); const f4v e0 = MFMA(a1, B0, c0);
            const f4v d1 = MFMA(a0, B1, c1); const f4v e1 = MFMA(a1, B1, c1);
            const f4v d2 = MFMA(a0, B2, c2); const f4v e2 = MFMA(a1, B2, c2);
            const f4v d3 = MFMA(a0, B3, c3); const f4v e3 = MFMA(a1, B3, c3);
            #pragma unroll
            for (int q = 0; q < 4; ++q) {
                s0[q] += fmaxf(d0[q], 0.f) + fmaxf(e0[q], 0.f);
                s1[q] += fmaxf(d1[q], 0.f) + fmaxf(e1[q], 0.f);
                s2[q] += fmaxf(d2[q], 0.f) + fmaxf(e2[q], 0.f);
                s3[q] += fmaxf(d3[q], 0.f) + fmaxf(e3[q], 0.f);
            }
        }
        #pragma unroll
        for (int q = 0; q < 4; ++q) {
            const int e = 4 * g + q;
            const int m = (e & 7) << 3;
            W[1024 + e*64 + (( 0 + r) ^ m)] = (_Float16)s0[q];
            W[1024 + e*64 + ((16 + r) ^ m)] = (_Float16)s1[q];
            W[1024 + e*64 + ((32 + r) ^ m)] = (_Float16)s2[q];
            W[1024 + e*64 + ((48 + r) ^ m)] = (_Float16)s3[q];
        }
    }

    if (g == 0) { barf[2*r] = bq0; barf[2*r + 1] = bq1; }

    // ================= C: pn = sn @ pnW2 + 16*pnb2 -> PNBUF ===================
    {
        h8v a0 = *(const h8v*)&W[r*64 + (( 0 + 8*g) ^ ((r&7)<<3))];
        h8v a1 = *(const h8v*)&W[r*64 + ((32 + 8*g) ^ ((r&7)<<3))];
        h8v b0 = FB[256 + 0*64 + l];
        h8v b1 = FB[256 + 1*64 + l];
        const float bb = 16.f * pnb2[r];
        f4v c = {bb, bb, bb, bb};
        f4v d = MFMA(a1, b1, MFMA(a0, b0, c));
        #pragma unroll
        for (int q = 0; q < 4; ++q) {
            const int row = 4 * g + q;
            W[2048 + row*32 + (r ^ ((row&3)<<3))] = (_Float16)d[q];
        }
    }
    // ================= D1: t = relu(pn @ rnW1 + rnb1) -> POOL =================
    {
        h8v a = *(const h8v*)&W[2048 + r*32 + ((8*g) ^ ((r&3)<<3))];
        #pragma unroll
        for (int nt = 0; nt < 4; ++nt) {
            h8v b = FB[384 + nt*64 + l];
            const float bb = rnb1[16*nt + r];
            f4v c = {bb, bb, bb, bb};
            f4v d = MFMA(a, b, c);
            #pragma unroll
            for (int q = 0; q < 4; ++q) {
                const int row = 4 * g + q;
                W[row*64 + ((16*nt + r) ^ ((row&7)<<3))] = (_Float16)fmaxf(d[q], 0.f);
            }
        }
    }
    // ================= D2: rn = t @ rnW2 + rnb2 -> HBUF cols 0..7 =============
    {
        h8v a0 = *(const h8v*)&W[r*64 + (( 0 + 8*g) ^ ((r&7)<<3))];
        h8v a1 = *(const h8v*)&W[r*64 + ((32 + 8*g) ^ ((r&7)<<3))];
        h8v b0 = FB[640 + 0*64 + l];
        h8v b1 = FB[640 + 1*64 + l];
        const float bb = (r < 8) ? rnb2[r & 7] : 0.f;
        f4v c = {bb, bb, bb, bb};
        f4v d = MFMA(a1, b1, MFMA(a0, b0, c));
        if (r < 8) {
            #pragma unroll
            for (int q = 0; q < 4; ++q) {
                const int row = 4 * g + q;
                W[2560 + row*32 + (r ^ ((row&3)<<3))] = (_Float16)d[q];
            }
        }
    }
    // ================= C': po = so @ poW2 + 32*pob2 -> PNBUF ==================
    {
        h8v a0 = *(const h8v*)&W[1024 + r*64 + (( 0 + 8*g) ^ ((r&7)<<3))];
        h8v a1 = *(const h8v*)&W[1024 + r*64 + ((32 + 8*g) ^ ((r&7)<<3))];
        h8v b0 = FB[1024 + 0*64 + l];
        h8v b1 = FB[1024 + 1*64 + l];
        const float bb = 32.f * pob2[r];
        f4v c = {bb, bb, bb, bb};
        f4v d = MFMA(a1, b1, MFMA(a0, b0, c));
        #pragma unroll
        for (int q = 0; q < 4; ++q) {
            const int row = 4 * g + q;
            W[2048 + row*32 + (r ^ ((row&3)<<3))] = (_Float16)d[q];
        }
    }
    // ================= D1': t2 = relu(po @ roW1 + rob1) -> POOL ===============
    {
        h8v a = *(const h8v*)&W[2048 + r*32 + ((8*g) ^ ((r&3)<<3))];
        #pragma unroll
        for (int nt = 0; nt < 4; ++nt) {
            h8v b = FB[1152 + nt*64 + l];
            const float bb = rob1[16*nt + r];
            f4v c = {bb, bb, bb, bb};
            f4v d = MFMA(a, b, c);
            #pragma unroll
            for (int q = 0; q < 4; ++q) {
                const int row = 4 * g + q;
                W[row*64 + ((16*nt + r) ^ ((row&7)<<3))] = (_Float16)fmaxf(d[q], 0.f);
            }
        }
    }
    // ================= D2': ro = t2 @ roW2 + rob2 -> HBUF cols 8..15 ==========
    {
        h8v a0 = *(const h8v*)&W[r*64 + (( 0 + 8*g) ^ ((r&7)<<3))];
        h8v a1 = *(const h8v*)&W[r*64 + ((32 + 8*g) ^ ((r&7)<<3))];
        h8v b0 = FB[1408 + 0*64 + l];
        h8v b1 = FB[1408 + 1*64 + l];
        const float bb = (r < 8) ? rob2[r & 7] : 0.f;
        f4v c = {bb, bb, bb, bb};
        f4v d = MFMA(a1, b1, MFMA(a0, b0, c));
        if (r < 8) {
            #pragma unroll
            for (int q = 0; q < 4; ++q) {
                const int row = 4 * g + q;
                W[2560 + row*32 + ((8 + r) ^ ((row&3)<<3))] = (_Float16)d[q];
            }
        }
    }
    // ================= goal cols 16,17 into HBUF ==============================
    if (g == 0) {
        const float gx = x[xrow + 1];
        const float gy = x[xrow + 2];
        W[2560 + r*32 + (16 ^ ((r&3)<<3))] = (_Float16)gx;
        W[2560 + r*32 + (17 ^ ((r&3)<<3))] = (_Float16)gy;
    }
    // ================= F: ha = relu(h @ psW1 + psb1) -> TBUF ==================
    {
        h8v a = *(const h8v*)&W[2560 + r*32 + ((8*g) ^ ((r&3)<<3))];
        #pragma unroll
        for (int nt = 0; nt < 4; ++nt) {
            h8v b = FB[1536 + nt*64 + l];
            const float bb = psb1[16*nt + r];
            f4v c = {bb, bb, bb, bb};
            f4v d = MFMA(a, b, c);
            #pragma unroll
            for (int q = 0; q < 4; ++q) {
                const int row = 4 * g + q;
                W[1024 + row*64 + ((16*nt + r) ^ ((row&7)<<3))] = (_Float16)fmaxf(d[q], 0.f);
            }
        }
    }
    // ================= G1: t2 = relu(ha @ psW2 + psb2) -> POOL ================
    {
        h8v a0 = *(const h8v*)&W[1024 + r*64 + (( 0 + 8*g) ^ ((r&7)<<3))];
        h8v a1 = *(const h8v*)&W[1024 + r*64 + ((32 + 8*g) ^ ((r&7)<<3))];
        #pragma unroll
        for (int nt = 0; nt < 4; ++nt) {
            h8v b0 = FB[1792 + (0*4 + nt)*64 + l];
            h8v b1 = FB[1792 + (1*4 + nt)*64 + l];
            const float bb = psb2[16*nt + r];
            f4v c = {bb, bb, bb, bb};
            f4v d = MFMA(a1, b1, MFMA(a0, b0, c));
            #pragma unroll
            for (int q = 0; q < 4; ++q) {
                const int row = 4 * g + q;
                W[row*64 + ((16*nt + r) ^ ((row&7)<<3))] = (_Float16)fmaxf(d[q], 0.f);
            }
        }
    }
    // ================= G2 + finale ============================================
    f4v dOut;
    {
        h8v a0 = *(const h8v*)&W[r*64 + (( 0 + 8*g) ^ ((r&7)<<3))];
        h8v a1 = *(const h8v*)&W[r*64 + ((32 + 8*g) ^ ((r&7)<<3))];
        h8v b0 = FB[2304 + 0*64 + l];
        h8v b1 = FB[2304 + 1*64 + l];
        const float bb = (r < 2) ? psb3[r & 1] : 0.f;
        f4v c = {bb, bb, bb, bb};
        dOut = MFMA(a1, b1, MFMA(a0, b0, c));
    }
    if (r < 2) {
        #pragma unroll
        for (int q = 0; q < 4; ++q) {
            const int e = 4 * g + q;
            const float o = dOut[q];
            const float bar = barf[e*2 + r];
            const float nz = noise[2 * (size_t)(eb + e) + r];
            const float av = tanhf(2.f * tanhf(o) + bar + nz);
            out[2 * (size_t)(eb + e) + r] = 2.f * av;
        }
    }
}

extern "C" void kernel_launch(void* const* d_in, const int* in_sizes, int n_in,
                              void* d_out, int out_size, void* d_ws, size_t ws_size,
                              hipStream_t stream) {
    const float* x    = (const float*)d_in[0];
    const float* nz   = (const float*)d_in[1];
    const float* pnW1 = (const float*)d_in[2];
    const float* pnb1 = (const float*)d_in[3];
    const float* pnW2 = (const float*)d_in[4];
    const float* pnb2 = (const float*)d_in[5];
    const float* rnW1 = (const float*)d_in[6];
    const float* rnb1 = (const float*)d_in[7];
    const float* rnW2 = (const float*)d_in[8];
    const float* rnb2 = (const float*)d_in[9];
    const float* poW1 = (const float*)d_in[10];
    const float* pob1 = (const float*)d_in[11];
    const float* poW2 = (const float*)d_in[12];
    const float* pob2 = (const float*)d_in[13];
    const float* roW1 = (const float*)d_in[14];
    const float* rob1 = (const float*)d_in[15];
    const float* roW2 = (const float*)d_in[16];
    const float* rob2 = (const float*)d_in[17];
    const float* psW1 = (const float*)d_in[18];
    const float* psb1 = (const float*)d_in[19];
    const float* psW2 = (const float*)d_in[20];
    const float* psb2 = (const float*)d_in[21];
    const float* psW3 = (const float*)d_in[22];
    const float* psb3 = (const float*)d_in[23];

    unsigned* ws = (unsigned*)d_ws;
    hipLaunchKernelGGL(prep_frags, dim3(1), dim3(256), 0, stream,
        pnW1, pnW2, rnW1, rnW2, poW1, poW2, roW1, roW2, psW1, psW2, psW3, ws);

    const int b = in_sizes[0] / XCOLS;
    hipLaunchKernelGGL(barrier_net_kernel, dim3(b / 64), dim3(256), 0, stream,
        x, nz, pnb1, pnb2, rnb1, rnb2, pob1, pob2, rob1, rob2,
        psb1, psb2, psb3, ws, (float*)d_out);
}

// Round 9
// 45.442 us; speedup vs baseline: 1.4078x; 1.3326x over previous
//
#include <hip/hip_runtime.h>

#define NN 16
#define NO 32
#define XCOLS 133

typedef _Float16 h8v __attribute__((ext_vector_type(8)));
typedef float f4v __attribute__((ext_vector_type(4)));
typedef unsigned ui4 __attribute__((ext_vector_type(4)));
typedef float f4u __attribute__((ext_vector_type(4), aligned(4)));

static __device__ __forceinline__ f4v MFMA(h8v a, h8v b, f4v c) {
    return __builtin_amdgcn_mfma_f32_16x16x32_f16(a, b, c, 0, 0, 0);
}
static __device__ __forceinline__ unsigned pkbits(float a, float b) {
    return __builtin_bit_cast(unsigned, __builtin_amdgcn_cvt_pkrtz(a, b));
}

// ---------------------------------------------------------------------------
// prep: pack weight matrices into MFMA B-fragment arrays in d_ws.
// B[k][col]: col = 16*nt + (lane&15), k = 32*kc + 8*(lane>>4) + j. Zero-padded
// beyond K,N. PARALLEL: 9728 items over 38 blocks x 256 threads.
// ---------------------------------------------------------------------------
__global__ void prep_frags(
    const float* __restrict__ pnW1, const float* __restrict__ pnW2,
    const float* __restrict__ rnW1, const float* __restrict__ rnW2,
    const float* __restrict__ poW1, const float* __restrict__ poW2,
    const float* __restrict__ roW1, const float* __restrict__ roW2,
    const float* __restrict__ psW1, const float* __restrict__ psW2,
    const float* __restrict__ psW3, unsigned* __restrict__ ws)
{
    const float* Ws[11] = {pnW1,pnW2,rnW1,rnW2,poW1,poW2,roW1,roW2,psW1,psW2,psW3};
    const int Kr[11]   = {4,64,16,64,2,64,16,64,18,64,64};
    const int Nr[11]   = {64,16,64,8,64,16,64,8,64,64,2};
    const int nkc[11]  = {1,2,1,2,1,2,1,2,1,2,2};
    const int nnt[11]  = {4,1,4,1,4,1,4,1,4,4,1};
    const int base[11] = {0,1024,1536,2560,3072,4096,4608,5632,6144,7168,9216};

    const int gid = blockIdx.x * 256 + threadIdx.x;   // 0..9727
    int start = 0;
    #pragma unroll
    for (int a2 = 0; a2 < 11; ++a2) {
        const int n = nkc[a2] * nnt[a2] * 256;
        if (gid >= start && gid < start + n) {
            const int i = gid - start;
            const float* Wm = Ws[a2];
            const int K = Kr[a2], N = Nr[a2], nt_n = nnt[a2];
            const int d = i & 3, lane = (i >> 2) & 63, t = i >> 8;
            const int nt = t % nt_n, kc = t / nt_n;
            const int k = kc * 32 + 8 * (lane >> 4) + 2 * d;
            const int col = nt * 16 + (lane & 15);
            const float v0 = (k     < K && col < N) ? Wm[(k    ) * N + col] : 0.f;
            const float v1 = (k + 1 < K && col < N) ? Wm[(k + 1) * N + col] : 0.f;
            ws[base[a2] + i] = pkbits(v0, v1);
        }
        start += n;
    }
}

// ---------------------------------------------------------------------------
// main: 64-thread (single-wave) blocks, one block = 16 batch elements.
// L1: point-loop, elements-as-rows, relu+pool in-register. Dense chain as
// verified in R7/R8. Barrier terms dedup'd across lane groups (g-shares +
// shfl_xor reduce), computed outside the MFMA hot loops.
// LDS (f16): POOL[16][64]@0, TBUF[16][64]@1024, PNBUF[16][32]@2048,
// HBUF[16][32]@2560, barf(32 f32)@3072. Total 3136 f16 = 6272 B/block.
// ---------------------------------------------------------------------------
__global__ __launch_bounds__(64, 8) void barrier_net_kernel(
    const float* __restrict__ x, const float* __restrict__ noise,
    const float* __restrict__ pnb1, const float* __restrict__ pnb2,
    const float* __restrict__ rnb1, const float* __restrict__ rnb2,
    const float* __restrict__ pob1, const float* __restrict__ pob2,
    const float* __restrict__ rob1, const float* __restrict__ rob2,
    const float* __restrict__ psb1, const float* __restrict__ psb2,
    const float* __restrict__ psb3,
    const unsigned* __restrict__ wsu, float* __restrict__ out)
{
    __shared__ _Float16 W[3136];

    const int l = threadIdx.x;
    const int r = l & 15;
    const int g = l >> 4;
    const int eb = blockIdx.x * 16;

    float* barf = (float*)(W + 3072);
    const h8v* FB = (const h8v*)wsu;

    {   // zero PNBUF+HBUF (1024 f16 = 512 dwords, 8 per lane)
        unsigned* z = (unsigned*)(W + 2048);
        #pragma unroll
        for (int i = 0; i < 8; ++i) z[l + 64 * i] = 0u;
    }

    const size_t xrow = (size_t)(eb + r) * XCOLS;

    // ================= barrier pass (dedup'd: g-group shares) =================
    {
        float bq0 = 0.f, bq1 = 0.f;
        const float* pxn = x + xrow + 5;
        #pragma unroll
        for (int jj = 0; jj < 4; ++jj) {
            const int j = 4 * g + jj;
            const float v0 = pxn[4*j], v1 = pxn[4*j + 1];
            const float nrm = sqrtf(v0*v0 + v1*v1);
            const float cc = 0.01f * __builtin_amdgcn_rcpf(nrm * (nrm - 0.3f));
            bq0 -= cc * v0; bq1 -= cc * v1;
        }
        const float* pxo = x + xrow + 69;
        #pragma unroll
        for (int jj = 0; jj < 8; ++jj) {
            const int j = 8 * g + jj;
            const float v0 = pxo[2*j], v1 = pxo[2*j + 1];
            const float nrm = sqrtf(v0*v0 + v1*v1);
            const float cc = 0.01f * __builtin_amdgcn_rcpf(nrm * (nrm - 0.5f));
            bq0 -= cc * v0; bq1 -= cc * v1;
        }
        bq0 += __shfl_xor(bq0, 16); bq0 += __shfl_xor(bq0, 32);
        bq1 += __shfl_xor(bq1, 16); bq1 += __shfl_xor(bq1, 32);
        if (g == 0) { barf[2*r] = bq0; barf[2*r + 1] = bq1; }
    }

    // ================= L1 neighbor: point-loop ================================
    {
        const h8v B0 = FB[0*64 + l], B1 = FB[1*64 + l];
        const h8v B2 = FB[2*64 + l], B3 = FB[3*64 + l];
        const f4v c0 = {pnb1[r], pnb1[r], pnb1[r], pnb1[r]};
        const f4v c1 = {pnb1[16+r], pnb1[16+r], pnb1[16+r], pnb1[16+r]};
        const f4v c2 = {pnb1[32+r], pnb1[32+r], pnb1[32+r], pnb1[32+r]};
        const f4v c3 = {pnb1[48+r], pnb1[48+r], pnb1[48+r], pnb1[48+r]};
        f4v s0 = {0,0,0,0}, s1 = {0,0,0,0}, s2 = {0,0,0,0}, s3 = {0,0,0,0};
        const float* px = x + xrow + 5;
        #pragma unroll 4
        for (int j = 0; j < NN; ++j) {
            const f4u v = *(const f4u*)(px + 4*j);
            ui4 au = {pkbits(v[0], v[1]), pkbits(v[2], v[3]), 0u, 0u};
            const h8v a = __builtin_bit_cast(h8v, au);
            const f4v d0 = MFMA(a, B0, c0);
            const f4v d1 = MFMA(a, B1, c1);
            const f4v d2 = MFMA(a, B2, c2);
            const f4v d3 = MFMA(a, B3, c3);
            #pragma unroll
            for (int q = 0; q < 4; ++q) {
                s0[q] += fmaxf(d0[q], 0.f); s1[q] += fmaxf(d1[q], 0.f);
                s2[q] += fmaxf(d2[q], 0.f); s3[q] += fmaxf(d3[q], 0.f);
            }
        }
        #pragma unroll
        for (int q = 0; q < 4; ++q) {
            const int e = 4 * g + q;
            const int m = (e & 7) << 3;
            W[e*64 + (( 0 + r) ^ m)] = (_Float16)s0[q];
            W[e*64 + ((16 + r) ^ m)] = (_Float16)s1[q];
            W[e*64 + ((32 + r) ^ m)] = (_Float16)s2[q];
            W[e*64 + ((48 + r) ^ m)] = (_Float16)s3[q];
        }
    }

    // ================= L1 obstacle: point-loop, 2 points/iter =================
    {
        const h8v B0 = FB[768 + 0*64 + l], B1 = FB[768 + 1*64 + l];
        const h8v B2 = FB[768 + 2*64 + l], B3 = FB[768 + 3*64 + l];
        const f4v c0 = {pob1[r], pob1[r], pob1[r], pob1[r]};
        const f4v c1 = {pob1[16+r], pob1[16+r], pob1[16+r], pob1[16+r]};
        const f4v c2 = {pob1[32+r], pob1[32+r], pob1[32+r], pob1[32+r]};
        const f4v c3 = {pob1[48+r], pob1[48+r], pob1[48+r], pob1[48+r]};
        f4v s0 = {0,0,0,0}, s1 = {0,0,0,0}, s2 = {0,0,0,0}, s3 = {0,0,0,0};
        const float* px = x + xrow + 69;
        #pragma unroll 2
        for (int t = 0; t < 16; ++t) {
            const f4u v = *(const f4u*)(px + 4*t);
            ui4 au0 = {pkbits(v[0], v[1]), 0u, 0u, 0u};
            ui4 au1 = {pkbits(v[2], v[3]), 0u, 0u, 0u};
            const h8v a0 = __builtin_bit_cast(h8v, au0);
            const h8v a1 = __builtin_bit_cast(h8v, au1);
            const f4v d0 = MFMA(a0, B0, c0); const f4v e0 = MFMA(a1, B0, c0);
            const f4v d1 = MFMA(a0, B1, c1); const f4v e1 = MFMA(a1, B1, c1);
            const f4v d2 = MFMA(a0, B2, c2); const f4v e2 = MFMA(a1, B2, c2);
            const f4v d3 = MFMA(a0, B3, c3); const f4v e3 = MFMA(a1, B3, c3);
            #pragma unroll
            for (int q = 0; q < 4; ++q) {
                s0[q] += fmaxf(d0[q], 0.f) + fmaxf(e0[q], 0.f);
                s1[q] += fmaxf(d1[q], 0.f) + fmaxf(e1[q], 0.f);
                s2[q] += fmaxf(d2[q], 0.f) + fmaxf(e2[q], 0.f);
                s3[q] += fmaxf(d3[q], 0.f) + fmaxf(e3[q], 0.f);
            }
        }
        #pragma unroll
        for (int q = 0; q < 4; ++q) {
            const int e = 4 * g + q;
            const int m = (e & 7) << 3;
            W[1024 + e*64 + (( 0 + r) ^ m)] = (_Float16)s0[q];
            W[1024 + e*64 + ((16 + r) ^ m)] = (_Float16)s1[q];
            W[1024 + e*64 + ((32 + r) ^ m)] = (_Float16)s2[q];
            W[1024 + e*64 + ((48 + r) ^ m)] = (_Float16)s3[q];
        }
    }

    // ================= C: pn = sn @ pnW2 + 16*pnb2 -> PNBUF ===================
    {
        h8v a0 = *(const h8v*)&W[r*64 + (( 0 + 8*g) ^ ((r&7)<<3))];
        h8v a1 = *(const h8v*)&W[r*64 + ((32 + 8*g) ^ ((r&7)<<3))];
        h8v b0 = FB[256 + 0*64 + l];
        h8v b1 = FB[256 + 1*64 + l];
        const float bb = 16.f * pnb2[r];
        f4v c = {bb, bb, bb, bb};
        f4v d = MFMA(a1, b1, MFMA(a0, b0, c));
        #pragma unroll
        for (int q = 0; q < 4; ++q) {
            const int row = 4 * g + q;
            W[2048 + row*32 + (r ^ ((row&3)<<3))] = (_Float16)d[q];
        }
    }
    // ================= D1: t = relu(pn @ rnW1 + rnb1) -> POOL =================
    {
        h8v a = *(const h8v*)&W[2048 + r*32 + ((8*g) ^ ((r&3)<<3))];
        #pragma unroll
        for (int nt = 0; nt < 4; ++nt) {
            h8v b = FB[384 + nt*64 + l];
            const float bb = rnb1[16*nt + r];
            f4v c = {bb, bb, bb, bb};
            f4v d = MFMA(a, b, c);
            #pragma unroll
            for (int q = 0; q < 4; ++q) {
                const int row = 4 * g + q;
                W[row*64 + ((16*nt + r) ^ ((row&7)<<3))] = (_Float16)fmaxf(d[q], 0.f);
            }
        }
    }
    // ================= D2: rn = t @ rnW2 + rnb2 -> HBUF cols 0..7 =============
    {
        h8v a0 = *(const h8v*)&W[r*64 + (( 0 + 8*g) ^ ((r&7)<<3))];
        h8v a1 = *(const h8v*)&W[r*64 + ((32 + 8*g) ^ ((r&7)<<3))];
        h8v b0 = FB[640 + 0*64 + l];
        h8v b1 = FB[640 + 1*64 + l];
        const float bb = (r < 8) ? rnb2[r & 7] : 0.f;
        f4v c = {bb, bb, bb, bb};
        f4v d = MFMA(a1, b1, MFMA(a0, b0, c));
        if (r < 8) {
            #pragma unroll
            for (int q = 0; q < 4; ++q) {
                const int row = 4 * g + q;
                W[2560 + row*32 + (r ^ ((row&3)<<3))] = (_Float16)d[q];
            }
        }
    }
    // ================= C': po = so @ poW2 + 32*pob2 -> PNBUF ==================
    {
        h8v a0 = *(const h8v*)&W[1024 + r*64 + (( 0 + 8*g) ^ ((r&7)<<3))];
        h8v a1 = *(const h8v*)&W[1024 + r*64 + ((32 + 8*g) ^ ((r&7)<<3))];
        h8v b0 = FB[1024 + 0*64 + l];
        h8v b1 = FB[1024 + 1*64 + l];
        const float bb = 32.f * pob2[r];
        f4v c = {bb, bb, bb, bb};
        f4v d = MFMA(a1, b1, MFMA(a0, b0, c));
        #pragma unroll
        for (int q = 0; q < 4; ++q) {
            const int row = 4 * g + q;
            W[2048 + row*32 + (r ^ ((row&3)<<3))] = (_Float16)d[q];
        }
    }
    // ================= D1': t2 = relu(po @ roW1 + rob1) -> POOL ===============
    {
        h8v a = *(const h8v*)&W[2048 + r*32 + ((8*g) ^ ((r&3)<<3))];
        #pragma unroll
        for (int nt = 0; nt < 4; ++nt) {
            h8v b = FB[1152 + nt*64 + l];
            const float bb = rob1[16*nt + r];
            f4v c = {bb, bb, bb, bb};
            f4v d = MFMA(a, b, c);
            #pragma unroll
            for (int q = 0; q < 4; ++q) {
                const int row = 4 * g + q;
                W[row*64 + ((16*nt + r) ^ ((row&7)<<3))] = (_Float16)fmaxf(d[q], 0.f);
            }
        }
    }
    // ================= D2': ro = t2 @ roW2 + rob2 -> HBUF cols 8..15 ==========
    {
        h8v a0 = *(const h8v*)&W[r*64 + (( 0 + 8*g) ^ ((r&7)<<3))];
        h8v a1 = *(const h8v*)&W[r*64 + ((32 + 8*g) ^ ((r&7)<<3))];
        h8v b0 = FB[1408 + 0*64 + l];
        h8v b1 = FB[1408 + 1*64 + l];
        const float bb = (r < 8) ? rob2[r & 7] : 0.f;
        f4v c = {bb, bb, bb, bb};
        f4v d = MFMA(a1, b1, MFMA(a0, b0, c));
        if (r < 8) {
            #pragma unroll
            for (int q = 0; q < 4; ++q) {
                const int row = 4 * g + q;
                W[2560 + row*32 + ((8 + r) ^ ((row&3)<<3))] = (_Float16)d[q];
            }
        }
    }
    // ================= goal cols 16,17 into HBUF ==============================
    if (g == 0) {
        const float gx = x[xrow + 1];
        const float gy = x[xrow + 2];
        W[2560 + r*32 + (16 ^ ((r&3)<<3))] = (_Float16)gx;
        W[2560 + r*32 + (17 ^ ((r&3)<<3))] = (_Float16)gy;
    }
    // ================= F: ha = relu(h @ psW1 + psb1) -> TBUF ==================
    {
        h8v a = *(const h8v*)&W[2560 + r*32 + ((8*g) ^ ((r&3)<<3))];
        #pragma unroll
        for (int nt = 0; nt < 4; ++nt) {
            h8v b = FB[1536 + nt*64 + l];
            const float bb = psb1[16*nt + r];
            f4v c = {bb, bb, bb, bb};
            f4v d = MFMA(a, b, c);
            #pragma unroll
            for (int q = 0; q < 4; ++q) {
                const int row = 4 * g + q;
                W[1024 + row*64 + ((16*nt + r) ^ ((row&7)<<3))] = (_Float16)fmaxf(d[q], 0.f);
            }
        }
    }
    // ================= G1: t2 = relu(ha @ psW2 + psb2) -> POOL ================
    {
        h8v a0 = *(const h8v*)&W[1024 + r*64 + (( 0 + 8*g) ^ ((r&7)<<3))];
        h8v a1 = *(const h8v*)&W[1024 + r*64 + ((32 + 8*g) ^ ((r&7)<<3))];
        #pragma unroll
        for (int nt = 0; nt < 4; ++nt) {
            h8v b0 = FB[1792 + (0*4 + nt)*64 + l];
            h8v b1 = FB[1792 + (1*4 + nt)*64 + l];
            const float bb = psb2[16*nt + r];
            f4v c = {bb, bb, bb, bb};
            f4v d = MFMA(a1, b1, MFMA(a0, b0, c));
            #pragma unroll
            for (int q = 0; q < 4; ++q) {
                const int row = 4 * g + q;
                W[row*64 + ((16*nt + r) ^ ((row&7)<<3))] = (_Float16)fmaxf(d[q], 0.f);
            }
        }
    }
    // ================= G2 + finale ============================================
    f4v dOut;
    {
        h8v a0 = *(const h8v*)&W[r*64 + (( 0 + 8*g) ^ ((r&7)<<3))];
        h8v a1 = *(const h8v*)&W[r*64 + ((32 + 8*g) ^ ((r&7)<<3))];
        h8v b0 = FB[2304 + 0*64 + l];
        h8v b1 = FB[2304 + 1*64 + l];
        const float bb = (r < 2) ? psb3[r & 1] : 0.f;
        f4v c = {bb, bb, bb, bb};
        dOut = MFMA(a1, b1, MFMA(a0, b0, c));
    }
    if (r < 2) {
        #pragma unroll
        for (int q = 0; q < 4; ++q) {
            const int e = 4 * g + q;
            const float o = dOut[q];
            const float bar = barf[e*2 + r];
            const float nz = noise[2 * (size_t)(eb + e) + r];
            const float av = tanhf(2.f * tanhf(o) + bar + nz);
            out[2 * (size_t)(eb + e) + r] = 2.f * av;
        }
    }
}

extern "C" void kernel_launch(void* const* d_in, const int* in_sizes, int n_in,
                              void* d_out, int out_size, void* d_ws, size_t ws_size,
                              hipStream_t stream) {
    const float* x    = (const float*)d_in[0];
    const float* nz   = (const float*)d_in[1];
    const float* pnW1 = (const float*)d_in[2];
    const float* pnb1 = (const float*)d_in[3];
    const float* pnW2 = (const float*)d_in[4];
    const float* pnb2 = (const float*)d_in[5];
    const float* rnW1 = (const float*)d_in[6];
    const float* rnb1 = (const float*)d_in[7];
    const float* rnW2 = (const float*)d_in[8];
    const float* rnb2 = (const float*)d_in[9];
    const float* poW1 = (const float*)d_in[10];
    const float* pob1 = (const float*)d_in[11];
    const float* poW2 = (const float*)d_in[12];
    const float* pob2 = (const float*)d_in[13];
    const float* roW1 = (const float*)d_in[14];
    const float* rob1 = (const float*)d_in[15];
    const float* roW2 = (const float*)d_in[16];
    const float* rob2 = (const float*)d_in[17];
    const float* psW1 = (const float*)d_in[18];
    const float* psb1 = (const float*)d_in[19];
    const float* psW2 = (const float*)d_in[20];
    const float* psb2 = (const float*)d_in[21];
    const float* psW3 = (const float*)d_in[22];
    const float* psb3 = (const float*)d_in[23];

    unsigned* ws = (unsigned*)d_ws;
    hipLaunchKernelGGL(prep_frags, dim3(38), dim3(256), 0, stream,
        pnW1, pnW2, rnW1, rnW2, poW1, poW2, roW1, roW2, psW1, psW2, psW3, ws);

    const int b = in_sizes[0] / XCOLS;
    hipLaunchKernelGGL(barrier_net_kernel, dim3(b / 16), dim3(64), 0, stream,
        x, nz, pnb1, pnb2, rnb1, rnb2, pob1, pob2, rob1, rob2,
        psb1, psb2, psb3, ws, (float*)d_out);
}